// Round 7
// baseline (874.080 us; speedup 1.0000x reference)
//
#include <hip/hip_runtime.h>
#include <stdint.h>

#define S_LEN 2048
#define BATCH 2
#define DMODEL 1024
#define NHEAD 16
#define DHEAD 64
#define HS ((size_t)S_LEN * DHEAD)   // 131072 elements per (b,h) slice

typedef float floatx4 __attribute__((ext_vector_type(4)));
typedef __bf16 bf16x8 __attribute__((ext_vector_type(8)));

__device__ __forceinline__ float bf2f(uint16_t u) {
  union { uint32_t i; float f; } x; x.i = ((uint32_t)u) << 16; return x.f;
}
__device__ __forceinline__ uint16_t f2bf(float f) {
  union { float f; uint32_t i; } x; x.f = f;
  uint32_t r = x.i + 0x7fffu + ((x.i >> 16) & 1u);
  return (uint16_t)(r >> 16);
}
__device__ __forceinline__ uint4 ld8(const void* p, size_t idx, int isf32) {
  if (isf32) {
    const float* f = (const float*)p + idx;
    float4 a = *(const float4*)f;
    float4 b = *(const float4*)(f + 4);
    uint4 r; uint16_t* rp = (uint16_t*)&r;
    rp[0] = f2bf(a.x); rp[1] = f2bf(a.y); rp[2] = f2bf(a.z); rp[3] = f2bf(a.w);
    rp[4] = f2bf(b.x); rp[5] = f2bf(b.y); rp[6] = f2bf(b.z); rp[7] = f2bf(b.w);
    return r;
  }
  return *(const uint4*)((const uint16_t*)p + idx);
}
__device__ __forceinline__ float ld1(const void* p, size_t idx, int isf32) {
  return isf32 ? ((const float*)p)[idx] : bf2f(((const uint16_t*)p)[idx]);
}

// ---------------------------------------------------------------------------
__global__ __launch_bounds__(256) void detect_dtype(const void* __restrict__ x,
                                                    int* __restrict__ flag) {
  __shared__ int cnt;
  if (threadIdx.x == 0) cnt = 0;
  __syncthreads();
  const uint16_t w = ((const uint16_t*)x)[threadIdx.x];
  const float av = fabsf(bf2f(w));
  if (!(av <= 256.f)) atomicAdd(&cnt, 1);
  __syncthreads();
  if (threadIdx.x == 0) *flag = (cnt >= 8) ? 1 : 0;
}

// ---------------------------------------------------------------------------
// qkv_chunk: strip 0: q -> qu (q+bu) AND qv (q+bv); strip 1: k; strip 2: v;
// strip 3: r. Block 128 rows x 64 cols, 4 waves of 32x64.
__global__ __launch_bounds__(256) void qkv_chunk(
    const void* __restrict__ x, const void* __restrict__ pe,
    const void* __restrict__ Wqkv, const void* __restrict__ Wrel,
    const void* __restrict__ bu, const void* __restrict__ bv,
    uint16_t* __restrict__ qub, uint16_t* __restrict__ qvb,
    uint16_t* __restrict__ kb, uint16_t* __restrict__ vb,
    uint16_t* __restrict__ rb, int z0, const int* __restrict__ pflag) {
  __shared__ uint16_t lA[128 * 32];
  __shared__ uint16_t lB[64 * 40];
  const int isf32 = *pflag;
  const int tid = threadIdx.x;
  const int lane = tid & 63;
  const int wave = tid >> 6;
  const int strip = blockIdx.x;
  const int zl = blockIdx.z;
  const int zg = z0 + zl;
  const int b = zg >> 4, h = zg & 15;

  const void* Abase;
  size_t aoff;  int lda;
  const void* Wbase;
  int ldb, col0;
  if (strip < 3) {
    Abase = x;   aoff = (size_t)b * DMODEL;  lda = 2 * DMODEL;
    Wbase = Wqkv; ldb = 3 * DMODEL;  col0 = strip * DMODEL + h * 64;
  } else {
    Abase = pe;  aoff = 0;                   lda = DMODEL;
    Wbase = Wrel; ldb = DMODEL;      col0 = h * 64;
  }
  const int sbase = blockIdx.y * 128;

  floatx4 acc[2][4];
  floatx4 zero4 = {0.f, 0.f, 0.f, 0.f};
#pragma unroll
  for (int i = 0; i < 2; i++)
#pragma unroll
    for (int j = 0; j < 4; j++) acc[i][j] = zero4;

  const int arow = tid >> 2;
  const int kcol = (tid & 3) * 8;
  const int kr = tid >> 3;
  const int nc = (tid & 7) * 8;

  for (int k0 = 0; k0 < DMODEL; k0 += 32) {
    *(uint4*)&lA[tid * 8] =
        ld8(Abase, aoff + (size_t)(sbase + arow) * lda + k0 + kcol, isf32);
    *(uint4*)&lA[2048 + tid * 8] =
        ld8(Abase, aoff + (size_t)(sbase + 64 + arow) * lda + k0 + kcol, isf32);
    uint4 wv = ld8(Wbase, (size_t)(k0 + kr) * ldb + col0 + nc, isf32);
    const uint16_t* wp = (const uint16_t*)&wv;
#pragma unroll
    for (int e = 0; e < 8; e++) lB[(nc + e) * 40 + kr] = wp[e];
    __syncthreads();
    bf16x8 af[2], bfr[4];
#pragma unroll
    for (int mi = 0; mi < 2; mi++)
      af[mi] = *(const bf16x8*)&lA[(wave * 32 + mi * 16 + (lane & 15)) * 32 + (lane >> 4) * 8];
#pragma unroll
    for (int ni = 0; ni < 4; ni++)
      bfr[ni] = *(const bf16x8*)&lB[(ni * 16 + (lane & 15)) * 40 + (lane >> 4) * 8];
#pragma unroll
    for (int mi = 0; mi < 2; mi++)
#pragma unroll
      for (int ni = 0; ni < 4; ni++)
        acc[mi][ni] = __builtin_amdgcn_mfma_f32_16x16x32_bf16(af[mi], bfr[ni], acc[mi][ni], 0, 0, 0);
    __syncthreads();
  }

#pragma unroll
  for (int mi = 0; mi < 2; mi++)
#pragma unroll
    for (int ni = 0; ni < 4; ni++)
#pragma unroll
      for (int v = 0; v < 4; v++) {
        const int s = sbase + wave * 32 + mi * 16 + (lane >> 4) * 4 + v;
        const int d = ni * 16 + (lane & 15);
        const size_t idx = (size_t)zl * HS + (size_t)s * 64 + d;
        const float val = acc[mi][ni][v];
        if (strip == 0) {
          qub[idx] = f2bf(val + ld1(bu, h * 64 + d, isf32));
          qvb[idx] = f2bf(val + ld1(bv, h * 64 + d, isf32));
        } else if (strip == 1) kb[idx] = f2bf(val);
        else if (strip == 2) vb[idx] = f2bf(val);
        else rb[idx] = f2bf(val);
      }
}

// ---------------------------------------------------------------------------
// Helpers for fused_score: 128x128 MFMA tile, A/B frags loaded directly from
// global [row][64] bf16 buffers (rows clamped to [0,2047]).
__device__ __forceinline__ void mm_tile(floatx4 acc[4][4],
    const uint16_t* __restrict__ A, int a0,
    const uint16_t* __restrict__ B, int b0,
    int wm, int wn, int m15, int q4) {
#pragma unroll
  for (int ks = 0; ks < 2; ks++) {
    const int koff = q4 * 8 + ks * 32;
    bf16x8 af[4], bfv[4];
#pragma unroll
    for (int mi = 0; mi < 4; mi++) {
      int r = a0 + wm * 64 + mi * 16 + m15;
      r = r < 0 ? 0 : (r > 2047 ? 2047 : r);
      af[mi] = *(const bf16x8*)(A + (size_t)r * 64 + koff);
    }
#pragma unroll
    for (int ni = 0; ni < 4; ni++) {
      int r = b0 + wn * 64 + ni * 16 + m15;
      r = r < 0 ? 0 : (r > 2047 ? 2047 : r);
      bfv[ni] = *(const bf16x8*)(B + (size_t)r * 64 + koff);
    }
#pragma unroll
    for (int mi = 0; mi < 4; mi++)
#pragma unroll
      for (int ni = 0; ni < 4; ni++)
        acc[mi][ni] = __builtin_amdgcn_mfma_f32_16x16x32_bf16(af[mi], bfv[ni], acc[mi][ni], 0, 0, 0);
  }
}

__device__ __forceinline__ void band_tile(uint16_t* __restrict__ Ldst,
    const uint16_t* __restrict__ A, int a0,
    const uint16_t* __restrict__ B, int b0,
    int wm, int wn, int m15, int q4) {
  floatx4 acc[4][4];
  floatx4 zero4 = {0.f, 0.f, 0.f, 0.f};
#pragma unroll
  for (int i = 0; i < 4; i++)
#pragma unroll
    for (int j = 0; j < 4; j++) acc[i][j] = zero4;
  mm_tile(acc, A, a0, B, b0, wm, wn, m15, q4);
#pragma unroll
  for (int mi = 0; mi < 4; mi++)
#pragma unroll
    for (int ni = 0; ni < 4; ni++)
#pragma unroll
      for (int v = 0; v < 4; v++)
        Ldst[(wm * 64 + mi * 16 + q4 * 4 + v) * 128 + wn * 64 + ni * 16 + m15] =
            f2bf(acc[mi][ni][v]);
}

// ---------------------------------------------------------------------------
// fused_score: per (i-tile, z): for each j-tile compute AC via MFMA, BD via
// on-the-fly c-band slabs in LDS + rel-shift gather, then P' = exp(S/8) written
// once (unnormalized; pv_gemm divides by row sums). No score RMW, no softmax.
__global__ __launch_bounds__(256) void fused_score(
    const uint16_t* __restrict__ qu, const uint16_t* __restrict__ qv,
    const uint16_t* __restrict__ kb, const uint16_t* __restrict__ rb,
    uint16_t* __restrict__ pbuf) {
  __shared__ uint16_t SL0[128 * 128];
  __shared__ uint16_t SL1[128 * 128];
  const int tid = threadIdx.x, lane = tid & 63, wave = tid >> 6;
  const int wm = wave >> 1, wn = wave & 1;
  const int m15 = lane & 15, q4 = lane >> 4;
  const int it = blockIdx.x, zl = blockIdx.y;
  const int r0 = it * 128;
  const uint16_t* quz = qu + (size_t)zl * HS;
  const uint16_t* qvz = qv + (size_t)zl * HS;
  const uint16_t* kbz = kb + (size_t)zl * HS;
  const uint16_t* rbz = rb + (size_t)zl * HS;
  uint16_t* pbz = pbuf + (size_t)zl * S_LEN * S_LEN;

  for (int jt = 0; jt < 16; jt++) {
    const int c0 = jt * 128;
    const int sA = 15 - it + jt;   // band1 lower slab (t units of 128)
    const int uB = jt - it;        // band2 upper u-slab

    // ---- band slabs (c = (q+bv)·r^T) ----
    if (jt <= it) {
      band_tile(SL0, qvz, r0, rbz, sA * 128, wm, wn, m15, q4);
      if (jt < it)
        band_tile(SL1, qvz, r0, rbz, (sA + 1) * 128, wm, wn, m15, q4);
    }
    if (jt >= it) {
      if (jt > it)
        band_tile(SL0, qvz, r0 + 1, rbz, (uB - 1) * 128 - 1, wm, wn, m15, q4);
      band_tile(SL1, qvz, r0 + 1, rbz, uB * 128 - 1, wm, wn, m15, q4);
    }
    __syncthreads();

    // ---- AC tile ----
    floatx4 acc[4][4];
    floatx4 zero4 = {0.f, 0.f, 0.f, 0.f};
#pragma unroll
    for (int i = 0; i < 4; i++)
#pragma unroll
      for (int j = 0; j < 4; j++) acc[i][j] = zero4;
    mm_tile(acc, quz, r0, kbz, c0, wm, wn, m15, q4);

    // ---- gather BD + exp + store ----
#pragma unroll
    for (int mi = 0; mi < 4; mi++)
#pragma unroll
      for (int ni = 0; ni < 4; ni++)
#pragma unroll
        for (int v = 0; v < 4; v++) {
          const int ii = wm * 64 + mi * 16 + q4 * 4 + v;
          const int jj = wn * 64 + ni * 16 + m15;
          const int i = r0 + ii, j = c0 + jj;
          float bd = 0.f;
          if (j <= i) {
            const int t = j + (S_LEN - 1) - i;
            const uint16_t* Lb = ((t >> 7) == sA) ? SL0 : SL1;
            bd = bf2f(Lb[ii * 128 + (t & 127)]);
          } else if (j >= i + 2) {
            const int u = j - i - 1;
            const uint16_t* Lb = ((u >> 7) == uB) ? SL1 : SL0;
            bd = bf2f(Lb[ii * 128 + (u & 127)]);
          }
          const float pr = __expf(fminf((acc[mi][ni][v] + bd) * 0.125f, 30.f));
          pbz[(size_t)i * S_LEN + j] = f2bf(pr);
        }
    __syncthreads();
  }
}

// ---------------------------------------------------------------------------
// pv_gemm: avec slice = P'[zl] @ v[zl], normalized by inline row sums of P'.
__global__ __launch_bounds__(256) void pv_gemm(
    const uint16_t* __restrict__ P, const uint16_t* __restrict__ vb,
    uint16_t* __restrict__ avec, int z0) {
  __shared__ uint16_t lA[128 * 32];
  __shared__ uint16_t lB[64 * 40];
  __shared__ float rsum[2][64][4];
  const int tid = threadIdx.x;
  const int lane = tid & 63;
  const int wave = tid >> 6;
  const int zl = blockIdx.z;
  const int zg = z0 + zl;
  const int b = zg >> 4, h = zg & 15;
  const uint16_t* Ab = P + (size_t)zl * S_LEN * S_LEN + (size_t)blockIdx.y * 128 * S_LEN;
  const uint16_t* Vb = vb + (size_t)zl * HS;

  floatx4 acc[2][4];
  floatx4 zero4 = {0.f, 0.f, 0.f, 0.f};
#pragma unroll
  for (int i = 0; i < 2; i++)
#pragma unroll
    for (int j = 0; j < 4; j++) acc[i][j] = zero4;

  const int arow = tid >> 2;
  const int kcol = (tid & 3) * 8;
  const int kr = tid >> 3;
  const int nc = (tid & 7) * 8;
  float ps0 = 0.f, ps1 = 0.f;

  for (int k0 = 0; k0 < S_LEN; k0 += 32) {
    uint4 a0 = *(const uint4*)(Ab + (size_t)arow * S_LEN + k0 + kcol);
    uint4 a1 = *(const uint4*)(Ab + (size_t)(64 + arow) * S_LEN + k0 + kcol);
    const uint16_t* p0 = (const uint16_t*)&a0;
    const uint16_t* p1 = (const uint16_t*)&a1;
#pragma unroll
    for (int e = 0; e < 8; e++) { ps0 += bf2f(p0[e]); ps1 += bf2f(p1[e]); }
    *(uint4*)&lA[tid * 8]        = a0;
    *(uint4*)&lA[2048 + tid * 8] = a1;
    uint4 vv = *(const uint4*)(Vb + (size_t)(k0 + kr) * 64 + nc);
    const uint16_t* vp = (const uint16_t*)&vv;
#pragma unroll
    for (int e = 0; e < 8; e++) lB[(nc + e) * 40 + kr] = vp[e];
    __syncthreads();
    bf16x8 af[2], bfr[4];
#pragma unroll
    for (int mi = 0; mi < 2; mi++)
      af[mi] = *(const bf16x8*)&lA[(wave * 32 + mi * 16 + (lane & 15)) * 32 + (lane >> 4) * 8];
#pragma unroll
    for (int ni = 0; ni < 4; ni++)
      bfr[ni] = *(const bf16x8*)&lB[(ni * 16 + (lane & 15)) * 40 + (lane >> 4) * 8];
#pragma unroll
    for (int mi = 0; mi < 2; mi++)
#pragma unroll
      for (int ni = 0; ni < 4; ni++)
        acc[mi][ni] = __builtin_amdgcn_mfma_f32_16x16x32_bf16(af[mi], bfr[ni], acc[mi][ni], 0, 0, 0);
    __syncthreads();
  }

  rsum[0][arow][tid & 3] = ps0;
  rsum[1][arow][tid & 3] = ps1;
  __syncthreads();

#pragma unroll
  for (int mi = 0; mi < 2; mi++)
#pragma unroll
    for (int ni = 0; ni < 4; ni++)
#pragma unroll
      for (int v = 0; v < 4; v++) {
        const int lr = wave * 32 + mi * 16 + (lane >> 4) * 4 + v;
        const float l = rsum[lr >> 6][lr & 63][0] + rsum[lr >> 6][lr & 63][1] +
                        rsum[lr >> 6][lr & 63][2] + rsum[lr >> 6][lr & 63][3];
        const int i = blockIdx.y * 128 + lr;
        const int d = ni * 16 + (lane & 15);
        avec[((size_t)i * BATCH + b) * DMODEL + h * 64 + d] = f2bf(acc[mi][ni][v] / l);
      }
}

// ---------------------------------------------------------------------------
// out_gemm: ybuf = avec (4096x1024) @ Wo + x.
__global__ __launch_bounds__(256) void out_gemm(
    const uint16_t* __restrict__ avec, const void* __restrict__ Wo,
    const void* __restrict__ x, uint16_t* __restrict__ ybuf,
    const int* __restrict__ pflag) {
  __shared__ uint16_t lA[128 * 32];
  __shared__ uint16_t lB[128 * 40];
  const int isf32 = *pflag;
  const int tid = threadIdx.x;
  const int lane = tid & 63;
  const int wave = tid >> 6;
  const int wm = wave >> 1, wn = wave & 1;
  const uint16_t* Ab = avec + (size_t)blockIdx.y * 128 * DMODEL;
  const int col0 = blockIdx.x * 128;

  floatx4 acc[4][4];
  floatx4 zero4 = {0.f, 0.f, 0.f, 0.f};
#pragma unroll
  for (int i = 0; i < 4; i++)
#pragma unroll
    for (int j = 0; j < 4; j++) acc[i][j] = zero4;

  const int arow = tid >> 2;
  const int kcol = (tid & 3) * 8;
  const int kr = tid >> 3;
  const int nc0 = (tid & 7) * 16;

  for (int k0 = 0; k0 < DMODEL; k0 += 32) {
    *(uint4*)&lA[tid * 8]        = *(const uint4*)(Ab + (size_t)arow * DMODEL + k0 + kcol);
    *(uint4*)&lA[2048 + tid * 8] = *(const uint4*)(Ab + (size_t)(64 + arow) * DMODEL + k0 + kcol);
    uint4 w0 = ld8(Wo, (size_t)(k0 + kr) * DMODEL + col0 + nc0, isf32);
    uint4 w1 = ld8(Wo, (size_t)(k0 + kr) * DMODEL + col0 + nc0 + 8, isf32);
    const uint16_t* p0 = (const uint16_t*)&w0;
    const uint16_t* p1 = (const uint16_t*)&w1;
#pragma unroll
    for (int e = 0; e < 8; e++) {
      lB[(nc0 + e) * 40 + kr] = p0[e];
      lB[(nc0 + 8 + e) * 40 + kr] = p1[e];
    }
    __syncthreads();
    bf16x8 af[4], bfr[4];
#pragma unroll
    for (int mi = 0; mi < 4; mi++)
      af[mi] = *(const bf16x8*)&lA[(wm * 64 + mi * 16 + (lane & 15)) * 32 + (lane >> 4) * 8];
#pragma unroll
    for (int ni = 0; ni < 4; ni++)
      bfr[ni] = *(const bf16x8*)&lB[(wn * 64 + ni * 16 + (lane & 15)) * 40 + (lane >> 4) * 8];
#pragma unroll
    for (int mi = 0; mi < 4; mi++)
#pragma unroll
      for (int ni = 0; ni < 4; ni++)
        acc[mi][ni] = __builtin_amdgcn_mfma_f32_16x16x32_bf16(af[mi], bfr[ni], acc[mi][ni], 0, 0, 0);
    __syncthreads();
  }

  const int r0 = blockIdx.y * 128 + wm * 64;
#pragma unroll
  for (int mi = 0; mi < 4; mi++)
#pragma unroll
    for (int ni = 0; ni < 4; ni++)
#pragma unroll
      for (int v = 0; v < 4; v++) {
        const int rg = r0 + mi * 16 + (lane >> 4) * 4 + v;
        const int cg = col0 + wn * 64 + ni * 16 + (lane & 15);
        const size_t o = (size_t)rg * DMODEL + cg;
        ybuf[o] = f2bf(acc[mi][ni][v] + ld1(x, o, isf32));
      }
}

// ---------------------------------------------------------------------------
__global__ __launch_bounds__(256) void ln_f32(
    const uint16_t* __restrict__ y, const void* __restrict__ gamma,
    const void* __restrict__ beta, float* __restrict__ out,
    const int* __restrict__ pflag) {
  const int isf32 = *pflag;
  const int row = blockIdx.x;
  const int tid = threadIdx.x;
  const int lane = tid & 63, wave = tid >> 6;
  const uint16_t* yr = y + (size_t)row * DMODEL;
  uint2 u = *(const uint2*)(yr + tid * 4);
  const uint16_t* up = (const uint16_t*)&u;
  float f[4];
  float s = 0.f, q = 0.f;
#pragma unroll
  for (int j = 0; j < 4; j++) { f[j] = bf2f(up[j]); s += f[j]; q += f[j] * f[j]; }
#pragma unroll
  for (int o = 32; o; o >>= 1) { s += __shfl_xor(s, o); q += __shfl_xor(q, o); }
  __shared__ float rs[4], rq[4];
  if (lane == 0) { rs[wave] = s; rq[wave] = q; }
  __syncthreads();
  s = rs[0] + rs[1] + rs[2] + rs[3];
  q = rq[0] + rq[1] + rq[2] + rq[3];
  const float mu = s * (1.f / DMODEL);
  const float var = fmaxf(q * (1.f / DMODEL) - mu * mu, 0.f);
  const float inv = rsqrtf(var + 1e-5f);
  float4 o4;
  float* op = (float*)&o4;
#pragma unroll
  for (int j = 0; j < 4; j++) {
    const int c = tid * 4 + j;
    float r = (f[j] - mu) * inv * ld1(gamma, c, isf32) + ld1(beta, c, isf32);
    if (!(r == r)) r = 1e4f;
    op[j] = r;
  }
  *(float4*)(out + (size_t)row * DMODEL + tid * 4) = o4;
}

__global__ __launch_bounds__(256) void sentinel_fill(float* __restrict__ out) {
  const size_t i = (size_t)blockIdx.x * 1024 + threadIdx.x * 4;
  out[i] = 1e6f; out[i + 1] = 1e6f; out[i + 2] = 1e6f; out[i + 3] = 1e6f;
}

extern "C" void kernel_launch(void* const* d_in, const int* in_sizes, int n_in,
                              void* d_out, int out_size, void* d_ws, size_t ws_size,
                              hipStream_t stream) {
  const void* x    = d_in[0];
  const void* pe   = d_in[1];
  const void* bu   = d_in[2];
  const void* bv   = d_in[3];
  const void* Wqkv = d_in[4];
  const void* Wrel = d_in[5];
  const void* Wo   = d_in[6];
  const void* gam  = d_in[7];
  const void* bet  = d_in[8];
  float* out = (float*)d_out;

  // Layout: [flag 256B][qu|qv|k|v|r: 5*ZC*256KB][P': ZC*8MB]
  const size_t per_z = 5 * HS * 2 + (size_t)S_LEN * S_LEN * 2;
  int ZC = 0;
  for (int c = 16; c >= 1; c >>= 1)
    if (256 + (size_t)c * per_z <= ws_size) { ZC = c; break; }

  const dim3 blk(256);
  if (ZC == 0) {
    sentinel_fill<<<dim3(4096), blk, 0, stream>>>(out);
    return;
  }

  int* flag = (int*)d_ws;
  uint16_t* qub = (uint16_t*)((char*)d_ws + 256);
  uint16_t* qvb = qub + (size_t)ZC * HS;
  uint16_t* kbuf = qvb + (size_t)ZC * HS;
  uint16_t* vbuf = kbuf + (size_t)ZC * HS;
  uint16_t* rbuf = vbuf + (size_t)ZC * HS;
  uint16_t* pbuf = rbuf + (size_t)ZC * HS;
  uint16_t* ybuf = pbuf;              // 8 MB, reused after P' dies
  uint16_t* avec = (uint16_t*)d_out;  // first 8 MB of d_out as bf16 scratch

  detect_dtype<<<dim3(1), blk, 0, stream>>>(x, flag);

  for (int z0 = 0; z0 < 32; z0 += ZC) {
    qkv_chunk<<<dim3(4, 16, ZC), blk, 0, stream>>>(
        x, pe, Wqkv, Wrel, bu, bv, qub, qvb, kbuf, vbuf, rbuf, z0, flag);
    fused_score<<<dim3(16, ZC), blk, 0, stream>>>(qub, qvb, kbuf, rbuf, pbuf);
    pv_gemm<<<dim3(1, 16, ZC), blk, 0, stream>>>(pbuf, vbuf, avec, z0);
  }

  out_gemm<<<dim3(8, 32, 1), blk, 0, stream>>>(avec, Wo, x, ybuf, flag);
  ln_f32<<<dim3(4096), blk, 0, stream>>>(ybuf, gam, bet, out, flag);
}